// Round 4
// baseline (1438.711 us; speedup 1.0000x reference)
//
#include <hip/hip_runtime.h>
#include <hip/hip_bf16.h>
#include <math.h>

// Problem constants
#define B_   32
#define L_   1024
#define H_   12
#define DV   64
#define MH   64
#define MM   128      // M = 2*Mh
#define HD   768      // hdim
#define BH_  384      // B*H

typedef unsigned int  uint32;
typedef unsigned short ushort16;
typedef __attribute__((ext_vector_type(4))) float f32x4;
typedef __attribute__((ext_vector_type(8))) short bf16x8;

__device__ __forceinline__ float bf2f(uint32 u) {
  return __uint_as_float(u << 16);
}
__device__ __forceinline__ ushort16 f2bf(float f) {
  uint32 x = __float_as_uint(f);
  x += 0x7FFFu + ((x >> 16) & 1u);   // RNE
  return (ushort16)(x >> 16);
}
__device__ __forceinline__ uint32 pack2bf(float a, float b) {
  return (uint32)f2bf(a) | ((uint32)f2bf(b) << 16);
}

// ---------------------------------------------------------------------------
// K0: convert x, Wqv to bf16; omega_scaled bf16 [h][m][d]; zero kl.
// ---------------------------------------------------------------------------
__global__ __launch_bounds__(256)
void k0_prep(const float* __restrict__ x, const float* __restrict__ Wqv,
             const float* __restrict__ omega_half, const float* __restrict__ log_ls,
             ushort16* __restrict__ xbf, ushort16* __restrict__ wqvbf,
             ushort16* __restrict__ omTbf, float* __restrict__ klbuf) {
  size_t i0 = (size_t)blockIdx.x * 256 + threadIdx.x;
  size_t stride = (size_t)gridDim.x * 256;
  for (size_t i = i0; i < (size_t)25165824 / 4; i += stride) {
    float4 v = ((const float4*)x)[i];
    uint2 w; w.x = pack2bf(v.x, v.y); w.y = pack2bf(v.z, v.w);
    ((uint2*)xbf)[i] = w;
  }
  for (size_t i = i0; i < (size_t)1179648 / 4; i += stride) {
    float4 v = ((const float4*)Wqv)[i];
    uint2 w; w.x = pack2bf(v.x, v.y); w.y = pack2bf(v.z, v.w);
    ((uint2*)wqvbf)[i] = w;
  }
  if (blockIdx.x < H_) {
    int h = blockIdx.x;
    for (int e = threadIdx.x; e < MH * DV; e += blockDim.x) {
      int m = e >> 6, d = e & 63;
      float scale = 1.41421356237f * expf(-log_ls[h * DV + d]);
      omTbf[h * MH * DV + m * DV + d] = f2bf(omega_half[h * DV * MH + d * MH + m] * scale);
    }
  }
  if (blockIdx.x == 0) {
    for (int e = threadIdx.x; e < BH_; e += blockDim.x) klbuf[e] = 0.f;
  }
}

// ---------------------------------------------------------------------------
// K1: qv = x @ Wqv^T in bf16 MFMA (16x16x32), 128x128 tile, BK=32.
//     Output bf16 permuted to [b][h][l][c], c in [0,128): c<64=q, c>=64=v.
// ---------------------------------------------------------------------------
__global__ __launch_bounds__(256)
void k1_qv_mfma(const ushort16* __restrict__ xbf, const ushort16* __restrict__ wqvbf,
                ushort16* __restrict__ qv) {
  __shared__ ushort16 As[128 * 40];
  __shared__ ushort16 Bs[128 * 40];
  int tid = threadIdx.x;
  int h  = blockIdx.x % 12;
  int tm = blockIdx.x / 12;
  int m0 = tm * 128;
  int n0 = h * 128;
  int wave = tid >> 6, lane = tid & 63;
  int wy = wave >> 1, wx = wave & 1;
  int mlane = lane & 15, q = lane >> 4;
  f32x4 acc[4][4];
#pragma unroll
  for (int i = 0; i < 4; i++)
#pragma unroll
    for (int j = 0; j < 4; j++) acc[i][j] = (f32x4){0.f, 0.f, 0.f, 0.f};

  int c0 = tid, c1 = tid + 256;
  int rowA0 = c0 >> 2, ka0 = (c0 & 3) * 8;
  int rowA1 = c1 >> 2, ka1 = (c1 & 3) * 8;

  for (int k0 = 0; k0 < HD; k0 += 32) {
    __syncthreads();
    uint4 a0 = *(const uint4*)&xbf[(size_t)(m0 + rowA0) * HD + k0 + ka0];
    uint4 a1 = *(const uint4*)&xbf[(size_t)(m0 + rowA1) * HD + k0 + ka1];
    uint4 b0 = *(const uint4*)&wqvbf[(size_t)(n0 + rowA0) * HD + k0 + ka0];
    uint4 b1 = *(const uint4*)&wqvbf[(size_t)(n0 + rowA1) * HD + k0 + ka1];
    *(uint4*)&As[rowA0 * 40 + ka0] = a0;
    *(uint4*)&As[rowA1 * 40 + ka1] = a1;
    *(uint4*)&Bs[rowA0 * 40 + ka0] = b0;
    *(uint4*)&Bs[rowA1 * 40 + ka1] = b1;
    __syncthreads();
    bf16x8 av[4], bv[4];
#pragma unroll
    for (int i = 0; i < 4; i++)
      av[i] = *(const bf16x8*)&As[(wy * 64 + i * 16 + mlane) * 40 + q * 8];
#pragma unroll
    for (int j = 0; j < 4; j++)
      bv[j] = *(const bf16x8*)&Bs[(wx * 64 + j * 16 + mlane) * 40 + q * 8];
#pragma unroll
    for (int i = 0; i < 4; i++)
#pragma unroll
      for (int j = 0; j < 4; j++)
        acc[i][j] = __builtin_amdgcn_mfma_f32_16x16x32_bf16(av[i], bv[j], acc[i][j], 0, 0, 0);
  }
#pragma unroll
  for (int i = 0; i < 4; i++) {
#pragma unroll
    for (int e = 0; e < 4; e++) {
      int gm = m0 + wy * 64 + i * 16 + q * 4 + e;
      int b = gm >> 10, l = gm & 1023;
      ushort16* dst = qv + ((((size_t)(b * 12 + h) << 10) | (unsigned)l) << 7);
#pragma unroll
      for (int j = 0; j < 4; j++) {
        int c = wx * 64 + j * 16 + mlane;
        dst[c] = f2bf(acc[i][j][e]);
      }
    }
  }
}

// ---------------------------------------------------------------------------
// K2: per (b,h): G = phi^T phi (128x128), C = phi^T v (128x64), all MFMA.
// ---------------------------------------------------------------------------
__global__ __launch_bounds__(256)
void k2_gram_mfma(const ushort16* __restrict__ qv, const ushort16* __restrict__ omTbf,
                  const float* __restrict__ phase, const float* __restrict__ log_sf,
                  char* __restrict__ Gbase, float* __restrict__ Cws) {
  __shared__ ushort16 PhT[128 * 136];   // 34816 B  phi^T [m][l]
  __shared__ ushort16 vT[64 * 136];     // 17408 B  v^T   [d][l]
  __shared__ float phaseS[MH];
  int bh = blockIdx.x;
  int h = bh % H_;
  int tid = threadIdx.x;
  int wave = tid >> 6, lane = tid & 63;
  int ml = lane & 15, qq = lane >> 4;
  if (tid < MH) phaseS[tid] = phase[h * MH + tid];
  float amp = sqrtf(expf(log_sf[h])) * 0.08838834764831845f;  // 1/sqrt(128)
  const ushort16* qp = qv + (size_t)bh * L_ * MM;
  const ushort16* Om = omTbf + h * MH * DV;
  f32x4 gacc[2][8];
  f32x4 cacc[2][4];
#pragma unroll
  for (int i = 0; i < 2; i++) {
#pragma unroll
    for (int j = 0; j < 8; j++) gacc[i][j] = (f32x4){0.f, 0.f, 0.f, 0.f};
#pragma unroll
    for (int j = 0; j < 4; j++) cacc[i][j] = (f32x4){0.f, 0.f, 0.f, 0.f};
  }
  __syncthreads();   // phaseS ready

  for (int l0 = 0; l0 < L_; l0 += 128) {
    // MFMA1: proj for this wave's 32 rows (K=64)
    f32x4 pacc[2][4];
#pragma unroll
    for (int i = 0; i < 2; i++)
#pragma unroll
      for (int j = 0; j < 4; j++) pacc[i][j] = (f32x4){0.f, 0.f, 0.f, 0.f};
#pragma unroll
    for (int k = 0; k < 2; k++) {
      bf16x8 af[2], bfm[4];
#pragma unroll
      for (int i = 0; i < 2; i++)
        af[i] = *(const bf16x8*)&qp[(size_t)(l0 + wave * 32 + i * 16 + ml) * MM + k * 32 + qq * 8];
#pragma unroll
      for (int j = 0; j < 4; j++)
        bfm[j] = *(const bf16x8*)&Om[(j * 16 + ml) * DV + k * 32 + qq * 8];
#pragma unroll
      for (int i = 0; i < 2; i++)
#pragma unroll
        for (int j = 0; j < 4; j++)
          pacc[i][j] = __builtin_amdgcn_mfma_f32_16x16x32_bf16(af[i], bfm[j], pacc[i][j], 0, 0, 0);
    }
    // stage v^T
    for (int u = tid; u < 1024; u += 256) {
      int row = u >> 3, g = u & 7;
      uint4 w = *(const uint4*)&qp[(size_t)(l0 + row) * MM + 64 + g * 8];
      vT[(g * 8 + 0) * 136 + row] = (ushort16)(w.x & 0xffffu);
      vT[(g * 8 + 1) * 136 + row] = (ushort16)(w.x >> 16);
      vT[(g * 8 + 2) * 136 + row] = (ushort16)(w.y & 0xffffu);
      vT[(g * 8 + 3) * 136 + row] = (ushort16)(w.y >> 16);
      vT[(g * 8 + 4) * 136 + row] = (ushort16)(w.z & 0xffffu);
      vT[(g * 8 + 5) * 136 + row] = (ushort16)(w.z >> 16);
      vT[(g * 8 + 6) * 136 + row] = (ushort16)(w.w & 0xffffu);
      vT[(g * 8 + 7) * 136 + row] = (ushort16)(w.w >> 16);
    }
    // phi (transposed store)
#pragma unroll
    for (int i = 0; i < 2; i++)
#pragma unroll
      for (int j = 0; j < 4; j++)
#pragma unroll
        for (int e = 0; e < 4; e++) {
          int l = wave * 32 + i * 16 + qq * 4 + e;   // local row
          int m = j * 16 + ml;
          float s = pacc[i][j][e] + phaseS[m];
          float sv, cv;
          sincosf(s, &sv, &cv);
          PhT[m * 136 + l]        = f2bf(amp * cv);
          PhT[(MH + m) * 136 + l] = f2bf(amp * sv);
        }
    __syncthreads();
    // G += PhT . PhT^T ; C += PhT . vT^T   (K = 128 local l)
#pragma unroll
    for (int k = 0; k < 4; k++) {
      bf16x8 af[2];
#pragma unroll
      for (int i = 0; i < 2; i++)
        af[i] = *(const bf16x8*)&PhT[(wave * 32 + i * 16 + ml) * 136 + k * 32 + qq * 8];
#pragma unroll
      for (int j = 0; j < 8; j++) {
        bf16x8 bfr = *(const bf16x8*)&PhT[(j * 16 + ml) * 136 + k * 32 + qq * 8];
#pragma unroll
        for (int i = 0; i < 2; i++)
          gacc[i][j] = __builtin_amdgcn_mfma_f32_16x16x32_bf16(af[i], bfr, gacc[i][j], 0, 0, 0);
      }
#pragma unroll
      for (int j = 0; j < 4; j++) {
        bf16x8 bvr = *(const bf16x8*)&vT[(j * 16 + ml) * 136 + k * 32 + qq * 8];
#pragma unroll
        for (int i = 0; i < 2; i++)
          cacc[i][j] = __builtin_amdgcn_mfma_f32_16x16x32_bf16(af[i], bvr, cacc[i][j], 0, 0, 0);
      }
    }
    __syncthreads();
  }
  float* Gp = (float*)(Gbase + (size_t)bh * 65536);
#pragma unroll
  for (int i = 0; i < 2; i++)
#pragma unroll
    for (int e = 0; e < 4; e++) {
      int m = wave * 32 + i * 16 + qq * 4 + e;
#pragma unroll
      for (int j = 0; j < 8; j++) Gp[m * MM + j * 16 + ml] = gacc[i][j][e];
    }
  float* Cp = Cws + (size_t)bh * MM * DV;
#pragma unroll
  for (int i = 0; i < 2; i++)
#pragma unroll
    for (int e = 0; e < 4; e++) {
      int m = wave * 32 + i * 16 + qq * 4 + e;
#pragma unroll
      for (int j = 0; j < 4; j++) Cp[m * DV + j * 16 + ml] = cacc[i][j][e];
    }
}

// ---------------------------------------------------------------------------
// K3: per (b,h): blocked Cholesky (NB=16); blocked inversion X = L^-1;
//     outputs Xbf (bf16 lower-tri row-major [n][m]) and DTbf (bf16 D^T [d][n])
//     into the G slot; D = X*C fp32 in place over C; KL pieces.
//     Phases 5/6: X from LDS (wave-uniform broadcast), Cp loads batched
//     8-wide for pipelining; triangular masks are compile-time static.
//     Sum order per output element identical to the serial version.
// ---------------------------------------------------------------------------
#define LB_(i,k) LBs[((i) << 7) + (((k) + (i)) & 127)]

__global__ __launch_bounds__(256)
void k3_factor(char* __restrict__ Gbase, float* __restrict__ Cws,
               const float* __restrict__ log_sigma2, float* __restrict__ klbuf) {
  __shared__ float LBs[MM * MM];     // 64 KB exactly
  int bh = blockIdx.x;
  int tid = threadIdx.x;
  float ls = log_sigma2[0];
  float sigma2 = expf(ls);
  float cjit = sigma2 + 1e-6f;
  const float* Gp = (const float*)(Gbase + (size_t)bh * 65536);
  for (int e = tid; e < MM * MM; e += 256) {
    int m = e >> 7, n = e & 127;
    float g = Gp[e];
    if (m == n) g += cjit;
    LB_(m, n) = g;
  }
  float klp = 0.f;

  // ---- Phase 1: blocked right-looking Cholesky, NB=16
  for (int P = 0; P < 8; P++) {
    int p0 = P * 16;
    __syncthreads();
    if (tid < 16) {
      int t = tid;
      float r[16];
#pragma unroll
      for (int k = 0; k < 16; k++) r[k] = LB_(p0 + t, p0 + k);
#pragma unroll
      for (int j = 0; j < 16; j++) {
        float djj = __shfl(r[j], j);
        float sd = sqrtf(djj);
        float rinv = 1.f / sd;
        if (t == j) r[j] = sd;
        else if (t > j) r[j] *= rinv;
#pragma unroll
        for (int k2 = 0; k2 < 16; k2++) {
          if (k2 > j) {
            float lkj = __shfl(r[j], k2);
            if (t >= k2) r[k2] = fmaf(-r[j], lkj, r[k2]);
          }
        }
      }
#pragma unroll
      for (int k = 0; k < 16; k++) if (k <= t) LB_(p0 + t, p0 + k) = r[k];
      klp += 64.f * logf(r[t]);       // 32*logdetA share
    }
    __syncthreads();
    int NR = 112 - p0;
    if (NR > 0 && tid < NR) {
      int gi = p0 + 16 + tid;
      float a[16];
#pragma unroll
      for (int k = 0; k < 16; k++) a[k] = LB_(gi, p0 + k);
#pragma unroll
      for (int j = 0; j < 16; j++) {
        float inv = 1.f / LB_(p0 + j, p0 + j);
        a[j] *= inv;
#pragma unroll
        for (int k = 0; k < 16; k++)
          if (k > j) a[k] = fmaf(-a[j], LB_(p0 + k, p0 + j), a[k]);
      }
#pragma unroll
      for (int k = 0; k < 16; k++) LB_(gi, p0 + k) = a[k];
    }
    __syncthreads();
    int S = NR;
    if (S > 0) {
      int base = p0 + 16;
      int t4 = S >> 2;
      int ntiles = t4 * t4;
      for (int tt = tid; tt < ntiles; tt += 256) {
        int ti = tt / t4, tj = tt % t4;
        if (ti < tj) continue;
        int gi = base + ti * 4, gj = base + tj * 4;
        float acc[4][4] = {};
#pragma unroll
        for (int j = 0; j < 16; j++) {
          float pa[4], pb[4];
#pragma unroll
          for (int a2 = 0; a2 < 4; a2++) pa[a2] = LB_(gi + a2, p0 + j);
#pragma unroll
          for (int b2 = 0; b2 < 4; b2++) pb[b2] = LB_(gj + b2, p0 + j);
#pragma unroll
          for (int a2 = 0; a2 < 4; a2++)
#pragma unroll
            for (int b2 = 0; b2 < 4; b2++)
              acc[a2][b2] = fmaf(pa[a2], pb[b2], acc[a2][b2]);
        }
#pragma unroll
        for (int a2 = 0; a2 < 4; a2++)
#pragma unroll
          for (int b2 = 0; b2 < 4; b2++)
            LB_(gi + a2, gj + b2) -= acc[a2][b2];
      }
    }
  }
  __syncthreads();

  // ---- Phase 2: invert the 8 diag blocks in place (zero-filled upper)
  {
    float xk[16];
    int cb = tid >> 4, cc = tid & 15;
    if (tid < 128) {
      int g = cb * 16;
#pragma unroll
      for (int rr = 0; rr < 16; rr++) {
        float s = (rr == cc) ? 1.f : 0.f;
#pragma unroll
        for (int k = 0; k < 16; k++)
          if (k < rr) s = fmaf(-LB_(g + rr, g + k), xk[k], s);
        xk[rr] = (rr >= cc) ? s / LB_(g + rr, g + rr) : 0.f;
      }
    }
    __syncthreads();
    if (tid < 128) {
      int g = cb * 16;
#pragma unroll
      for (int rr = 0; rr < 16; rr++) LB_(g + rr, g + cc) = xk[rr];
    }
    __syncthreads();
  }

  // ---- Phase 3: off-diag blocks of X = L^-1
  {
    int r16 = tid >> 4, c16 = tid & 15;
    for (int J = 6; J >= 0; J--) {
      int nb = 7 - J;
      float yv[7];
#pragma unroll
      for (int q = 0; q < 7; q++) {
        if (q < nb) {
          int K = J + 1 + q;
          float s = 0.f;
#pragma unroll
          for (int c2 = 0; c2 < 16; c2++)
            s = fmaf(LB_(K * 16 + r16, J * 16 + c2), LB_(J * 16 + c2, J * 16 + c16), s);
          yv[q] = s;
        }
      }
      __syncthreads();
#pragma unroll
      for (int q = 0; q < 7; q++)
        if (q < nb) LB_((J + 1 + q) * 16 + r16, J * 16 + c16) = yv[q];
      __syncthreads();
      float xv[7];
#pragma unroll
      for (int q = 0; q < 7; q++) {
        if (q < nb) {
          int I = J + 1 + q;
          float s = 0.f;
          for (int K = J + 1; K <= I; K++) {
#pragma unroll
            for (int k = 0; k < 16; k++)
              s = fmaf(LB_(I * 16 + r16, K * 16 + k), LB_(K * 16 + k, J * 16 + c16), s);
          }
          xv[q] = -s;
        }
      }
      __syncthreads();
#pragma unroll
      for (int q = 0; q < 7; q++)
        if (q < nb) LB_((J + 1 + q) * 16 + r16, J * 16 + c16) = xv[q];
      __syncthreads();
    }
  }

  // ---- Phase 4: write Xbf (bf16, zeros above diag); tr(Ainv) = ||X||_F^2
  ushort16* Xb = (ushort16*)(Gbase + (size_t)bh * 65536);
  for (int e = tid; e < MM * MM; e += 256) {
    int r = e >> 7, c = e & 127;
    float xv2 = (c <= r) ? LB_(r, c) : 0.f;
    Xb[e] = f2bf(xv2);
    klp += 32.f * sigma2 * xv2 * xv2;
  }

  // ---- Phase 5: D = X * C fp32, in place over C. Wave w owns rows
  //      n in [32w,32w+32), lane = d. X from LDS (wave-uniform broadcast,
  //      conflict-free); 8 batched coalesced Cp loads per block pipeline.
  //      Sum is exactly m = 0..n ascending (tail masks are static).
  float* Cp = Cws + (size_t)bh * MM * DV;
  {
    int w = tid >> 6, lane = tid & 63;
    int nbase = w * 32;
    float acc[32];
#pragma unroll
    for (int i = 0; i < 32; i++) acc[i] = 0.f;
    // full blocks: m in [0, 32w) — all m < n for every owned row
    for (int mb = 0; mb < nbase; mb += 8) {
      float c8[8];
#pragma unroll
      for (int u = 0; u < 8; u++) c8[u] = Cp[(mb + u) * 64 + lane];
#pragma unroll
      for (int i = 0; i < 32; i++) {
        int n = nbase + i;
        float s = acc[i];
#pragma unroll
        for (int u = 0; u < 8; u++) s = fmaf(LB_(n, mb + u), c8[u], s);
        acc[i] = s;
      }
    }
    // tail blocks: m in [32w, 32w+32), static mask m <= n
#pragma unroll
    for (int tb = 0; tb < 4; tb++) {
      int mb = nbase + tb * 8;
      float c8[8];
#pragma unroll
      for (int u = 0; u < 8; u++) c8[u] = Cp[(mb + u) * 64 + lane];
#pragma unroll
      for (int i = 0; i < 32; i++) {
        int n = nbase + i;
        float s = acc[i];
#pragma unroll
        for (int u = 0; u < 8; u++)
          if (tb * 8 + u <= i) s = fmaf(LB_(n, mb + u), c8[u], s);
        acc[i] = s;
      }
    }
    __syncthreads();   // all C reads (by every wave) done before any D store
#pragma unroll
    for (int i = 0; i < 32; i++) Cp[(nbase + i) * 64 + lane] = acc[i];
  }
  __syncthreads();     // D stores drained (same pattern as passing baseline)

  // ---- Phase 6: mu_norm2 = ||X^T D||_F^2. Wave w owns rows m in
  //      [32w,32w+32), lane = d. X^T[m][n] = LB_(n,m) (uniform broadcast).
  //      Sum is exactly n = m..127 ascending (tail masks are static).
  {
    int w = tid >> 6, lane = tid & 63;
    int mbase = w * 32;
    float acc[32];
#pragma unroll
    for (int i = 0; i < 32; i++) acc[i] = 0.f;
    // tail blocks first: n in [32w, 32w+32), static mask n >= m
#pragma unroll
    for (int tb = 0; tb < 4; tb++) {
      int nb = mbase + tb * 8;
      float d8[8];
#pragma unroll
      for (int u = 0; u < 8; u++) d8[u] = Cp[(nb + u) * 64 + lane];
#pragma unroll
      for (int i = 0; i < 32; i++) {
        float s = acc[i];
#pragma unroll
        for (int u = 0; u < 8; u++)
          if (tb * 8 + u >= i) s = fmaf(LB_(nb + u, mbase + i), d8[u], s);
        acc[i] = s;
      }
    }
    // full blocks: n in [32w+32, 128) — all n > m for every owned row
    for (int nb = mbase + 32; nb < 128; nb += 8) {
      float d8[8];
#pragma unroll
      for (int u = 0; u < 8; u++) d8[u] = Cp[(nb + u) * 64 + lane];
#pragma unroll
      for (int i = 0; i < 32; i++) {
        float s = acc[i];
#pragma unroll
        for (int u = 0; u < 8; u++) s = fmaf(LB_(nb + u, mbase + i), d8[u], s);
        acc[i] = s;
      }
    }
#pragma unroll
    for (int i = 0; i < 32; i++) klp += 0.5f * acc[i] * acc[i];
  }

  // ---- Phase 7: DTbf = bf16(D^T) [d][n]
  ushort16* DTb = (ushort16*)(Gbase + (size_t)bh * 65536 + 32768);
  for (int e = tid; e < DV * MM; e += 256) {
    int d = e >> 7, n = e & 127;
    DTb[e] = f2bf(Cp[n * DV + d]);
  }
  if (tid == 0) klp += -4096.f - 4096.f * ls;   // 0.5*(-k - Dv*M*log(sigma2))
  atomicAdd(&klbuf[bh], klp);
}

// ---------------------------------------------------------------------------
// K4: per (bh, 128-row chunk): proj=q@Om^T (MFMA) -> sincos -> phi(LDS) ->
//     z = phi @ X^T (MFMA, X from global bf16) -> var rowsum+shfl ->
//     mean = z @ DT^T (MFMA) -> sample -> coalesced store via LDS.
// ---------------------------------------------------------------------------
__global__ __launch_bounds__(256)
void k4_sample_mfma(const ushort16* __restrict__ qv, const ushort16* __restrict__ omTbf,
                    const float* __restrict__ phase, const float* __restrict__ log_sf,
                    const float* __restrict__ log_sigma2, const char* __restrict__ Gbase,
                    const float* __restrict__ eps, ushort16* __restrict__ sfeat) {
  __shared__ ushort16 ABuf[128 * 136];   // 34816 B  phi, then z (bf16, [l][·])
  __shared__ ushort16 obuf[128 * 72];    // 18432 B  sample staging
  __shared__ float stdS[128];
  __shared__ float phaseS[MH];
  int blk = blockIdx.x;
  int bh = blk >> 3, l0 = (blk & 7) << 7;
  int h = bh % H_, b = bh / H_;
  int tid = threadIdx.x;
  int wave = tid >> 6, lane = tid & 63;
  int ml = lane & 15, qq = lane >> 4;
  if (tid < MH) phaseS[tid] = phase[h * MH + tid];
  float amp = sqrtf(expf(log_sf[h])) * 0.08838834764831845f;
  float sigma2 = expf(log_sigma2[0]);
  const ushort16* qp = qv + ((size_t)bh * L_ + l0) * MM;
  const ushort16* Om = omTbf + h * MH * DV;
  const ushort16* Xb = (const ushort16*)(Gbase + (size_t)bh * 65536);
  const ushort16* DT = (const ushort16*)(Gbase + (size_t)bh * 65536 + 32768);

  // MFMA1: proj (K=64)
  f32x4 pacc[2][4];
#pragma unroll
  for (int i = 0; i < 2; i++)
#pragma unroll
    for (int j = 0; j < 4; j++) pacc[i][j] = (f32x4){0.f, 0.f, 0.f, 0.f};
#pragma unroll
  for (int k = 0; k < 2; k++) {
    bf16x8 af[2], bfm[4];
#pragma unroll
    for (int i = 0; i < 2; i++)
      af[i] = *(const bf16x8*)&qp[(size_t)(wave * 32 + i * 16 + ml) * MM + k * 32 + qq * 8];
#pragma unroll
    for (int j = 0; j < 4; j++)
      bfm[j] = *(const bf16x8*)&Om[(j * 16 + ml) * DV + k * 32 + qq * 8];
#pragma unroll
    for (int i = 0; i < 2; i++)
#pragma unroll
      for (int j = 0; j < 4; j++)
        pacc[i][j] = __builtin_amdgcn_mfma_f32_16x16x32_bf16(af[i], bfm[j], pacc[i][j], 0, 0, 0);
  }
  __syncthreads();   // phaseS ready
  // sincos -> phi rows (wave-private rows of ABuf)
#pragma unroll
  for (int i = 0; i < 2; i++)
#pragma unroll
    for (int j = 0; j < 4; j++)
#pragma unroll
      for (int e = 0; e < 4; e++) {
        int l = wave * 32 + i * 16 + qq * 4 + e;
        int m = j * 16 + ml;
        float s = pacc[i][j][e] + phaseS[m];
        float sv, cv;
        sincosf(s, &sv, &cv);
        ABuf[l * 136 + m]      = f2bf(amp * cv);
        ABuf[l * 136 + 64 + m] = f2bf(amp * sv);
      }
  // MFMA2: z = phi @ X^T (K=128)
  f32x4 zacc[2][8];
#pragma unroll
  for (int i = 0; i < 2; i++)
#pragma unroll
    for (int j = 0; j < 8; j++) zacc[i][j] = (f32x4){0.f, 0.f, 0.f, 0.f};
#pragma unroll
  for (int k = 0; k < 4; k++) {
    bf16x8 af[2];
#pragma unroll
    for (int i = 0; i < 2; i++)
      af[i] = *(const bf16x8*)&ABuf[(wave * 32 + i * 16 + ml) * 136 + k * 32 + qq * 8];
#pragma unroll
    for (int j = 0; j < 8; j++) {
      bf16x8 bfr = *(const bf16x8*)&Xb[(j * 16 + ml) * MM + k * 32 + qq * 8];
#pragma unroll
      for (int i = 0; i < 2; i++)
        zacc[i][j] = __builtin_amdgcn_mfma_f32_16x16x32_bf16(af[i], bfr, zacc[i][j], 0, 0, 0);
    }
  }
  // var = sigma2 * ||z_row||^2 ; std to LDS
#pragma unroll
  for (int i = 0; i < 2; i++)
#pragma unroll
    for (int e = 0; e < 4; e++) {
      float vs = 0.f;
#pragma unroll
      for (int j = 0; j < 8; j++) vs += zacc[i][j][e] * zacc[i][j][e];
      vs += __shfl_xor(vs, 1);
      vs += __shfl_xor(vs, 2);
      vs += __shfl_xor(vs, 4);
      vs += __shfl_xor(vs, 8);
      if (ml == 0) stdS[wave * 32 + i * 16 + qq * 4 + e] = sqrtf(fmaxf(sigma2 * vs, 0.f));
    }
  // z -> ABuf (overwrite phi; wave-private rows)
#pragma unroll
  for (int i = 0; i < 2; i++)
#pragma unroll
    for (int j = 0; j < 8; j++)
#pragma unroll
      for (int e = 0; e < 4; e++) {
        int l = wave * 32 + i * 16 + qq * 4 + e;
        ABuf[l * 136 + j * 16 + ml] = f2bf(zacc[i][j][e]);
      }
  // MFMA3: mean = z @ DT^T (K=128)
  f32x4 macc[2][4];
#pragma unroll
  for (int i = 0; i < 2; i++)
#pragma unroll
    for (int j = 0; j < 4; j++) macc[i][j] = (f32x4){0.f, 0.f, 0.f, 0.f};
#pragma unroll
  for (int k = 0; k < 4; k++) {
    bf16x8 af[2];
#pragma unroll
    for (int i = 0; i < 2; i++)
      af[i] = *(const bf16x8*)&ABuf[(wave * 32 + i * 16 + ml) * 136 + k * 32 + qq * 8];
#pragma unroll
    for (int j = 0; j < 4; j++) {
      bf16x8 bfr = *(const bf16x8*)&DT[(j * 16 + ml) * MM + k * 32 + qq * 8];
#pragma unroll
      for (int i = 0; i < 2; i++)
        macc[i][j] = __builtin_amdgcn_mfma_f32_16x16x32_bf16(af[i], bfr, macc[i][j], 0, 0, 0);
    }
  }
  // sample + stage
  const float* ep = eps + ((size_t)bh * L_ + l0) * DV;
#pragma unroll
  for (int i = 0; i < 2; i++)
#pragma unroll
    for (int j = 0; j < 4; j++)
#pragma unroll
      for (int e = 0; e < 4; e++) {
        int l = wave * 32 + i * 16 + qq * 4 + e;
        int d = j * 16 + ml;
        float smp = macc[i][j][e] + stdS[l] * ep[l * DV + d];
        obuf[l * 72 + d] = f2bf(smp);
      }
  __syncthreads();
  // coalesced store: row = 64 bf16 = 4 uint4
  ushort16* sp = sfeat + ((size_t)b * L_ + l0) * HD + h * DV;
  for (int u = tid; u < 512; u += 256) {
    int row = u >> 2, part = u & 3;
    uint4 val = *(const uint4*)&obuf[row * 72 + part * 8];
    *(uint4*)&sp[(size_t)row * HD + part * 8] = val;
  }
}

// ---------------------------------------------------------------------------
// K5: out = sfeat @ Wo^T + b, bf16 MFMA (Wo converted during staging), fp32 out
// ---------------------------------------------------------------------------
__global__ __launch_bounds__(256)
void k5_out_mfma(const ushort16* __restrict__ sfeat, const float* __restrict__ Wo,
                 const float* __restrict__ bias, float* __restrict__ outp) {
  __shared__ ushort16 As[128 * 40];
  __shared__ ushort16 Bs[128 * 40];
  int tid = threadIdx.x;
  int tn = blockIdx.x % 6;
  int tm = blockIdx.x / 6;
  int m0 = tm * 128, n0 = tn * 128;
  int wave = tid >> 6, lane = tid & 63;
  int wy = wave >> 1, wx = wave & 1;
  int mlane = lane & 15, q = lane >> 4;
  f32x4 acc[4][4];
#pragma unroll
  for (int i = 0; i < 4; i++)
#pragma unroll
    for (int j = 0; j < 4; j++) acc[i][j] = (f32x4){0.f, 0.f, 0.f, 0.f};

  int c0 = tid, c1 = tid + 256;
  int rowA0 = c0 >> 2, ka0 = (c0 & 3) * 8;
  int rowA1 = c1 >> 2, ka1 = (c1 & 3) * 8;

  for (int k0 = 0; k0 < HD; k0 += 32) {
    __syncthreads();
    uint4 a0 = *(const uint4*)&sfeat[(size_t)(m0 + rowA0) * HD + k0 + ka0];
    uint4 a1 = *(const uint4*)&sfeat[(size_t)(m0 + rowA1) * HD + k0 + ka1];
    float4 w00 = *(const float4*)&Wo[(size_t)(n0 + rowA0) * HD + k0 + ka0];
    float4 w01 = *(const float4*)&Wo[(size_t)(n0 + rowA0) * HD + k0 + ka0 + 4];
    float4 w10 = *(const float4*)&Wo[(size_t)(n0 + rowA1) * HD + k0 + ka1];
    float4 w11 = *(const float4*)&Wo[(size_t)(n0 + rowA1) * HD + k0 + ka1 + 4];
    uint4 b0, b1;
    b0.x = pack2bf(w00.x, w00.y); b0.y = pack2bf(w00.z, w00.w);
    b0.z = pack2bf(w01.x, w01.y); b0.w = pack2bf(w01.z, w01.w);
    b1.x = pack2bf(w10.x, w10.y); b1.y = pack2bf(w10.z, w10.w);
    b1.z = pack2bf(w11.x, w11.y); b1.w = pack2bf(w11.z, w11.w);
    *(uint4*)&As[rowA0 * 40 + ka0] = a0;
    *(uint4*)&As[rowA1 * 40 + ka1] = a1;
    *(uint4*)&Bs[rowA0 * 40 + ka0] = b0;
    *(uint4*)&Bs[rowA1 * 40 + ka1] = b1;
    __syncthreads();
    bf16x8 av[4], bv[4];
#pragma unroll
    for (int i = 0; i < 4; i++)
      av[i] = *(const bf16x8*)&As[(wy * 64 + i * 16 + mlane) * 40 + q * 8];
#pragma unroll
    for (int j = 0; j < 4; j++)
      bv[j] = *(const bf16x8*)&Bs[(wx * 64 + j * 16 + mlane) * 40 + q * 8];
#pragma unroll
    for (int i = 0; i < 4; i++)
#pragma unroll
      for (int j = 0; j < 4; j++)
        acc[i][j] = __builtin_amdgcn_mfma_f32_16x16x32_bf16(av[i], bv[j], acc[i][j], 0, 0, 0);
  }
  float bsv[4];
#pragma unroll
  for (int j = 0; j < 4; j++) bsv[j] = bias[n0 + wx * 64 + j * 16 + mlane];
#pragma unroll
  for (int i = 0; i < 4; i++) {
#pragma unroll
    for (int e = 0; e < 4; e++) {
      int gm = m0 + wy * 64 + i * 16 + q * 4 + e;
#pragma unroll
      for (int j = 0; j < 4; j++) {
        int gn = n0 + wx * 64 + j * 16 + mlane;
        outp[(size_t)gm * HD + gn] = acc[i][j][e] + bsv[j];
      }
    }
  }
}

// ---------------------------------------------------------------------------
// K6: kl = sum(klbuf)/B  -> out[25165824]
// ---------------------------------------------------------------------------
__global__ void k6_kl(const float* __restrict__ klbuf, float* __restrict__ outp) {
  __shared__ float red[2];
  int tid = threadIdx.x;   // 128
  float s = 0.f;
  for (int e = tid; e < BH_; e += 128) s += klbuf[e];
  for (int off = 32; off >= 1; off >>= 1) s += __shfl_xor(s, off);
  if ((tid & 63) == 0) red[tid >> 6] = s;
  __syncthreads();
  if (tid == 0) outp[(size_t)B_ * L_ * HD] = (red[0] + red[1]) * (1.f / 32.f);
}

// ---------------------------------------------------------------------------
extern "C" void kernel_launch(void* const* d_in, const int* in_sizes, int n_in,
                              void* d_out, int out_size, void* d_ws, size_t ws_size,
                              hipStream_t stream) {
  (void)in_sizes; (void)n_in; (void)out_size; (void)ws_size;
  const float* x       = (const float*)d_in[0];
  const float* Wqv     = (const float*)d_in[1];
  const float* log_sf  = (const float*)d_in[2];
  const float* log_ls  = (const float*)d_in[3];
  const float* log_s2  = (const float*)d_in[4];
  const float* omega_h = (const float*)d_in[5];
  const float* phase   = (const float*)d_in[6];
  const float* Wo      = (const float*)d_in[7];
  const float* Wob     = (const float*)d_in[8];
  const float* eps     = (const float*)d_in[9];
  float* outp = (float*)d_out;

  // Workspace layout (total 188,941,824 bytes):
  char* ws = (char*)d_ws;
  ushort16* qv    = (ushort16*)(ws);                    // bf16 [b][h][l][128]  100,663,296 B
  ushort16* xbf   = (ushort16*)(ws + 100663296);        // bf16 x; later sfeat   50,331,648 B
  ushort16* sfeat = xbf;                                // alias (k1 done with xbf before k4)
  ushort16* omTbf = (ushort16*)(ws + 150994944);        // bf16 [h][m][d]            98,304 B
  char*     Gbase = ws + 151191552;                     // 384 x 65536 B slots:
                                                        //  G fp32 -> Xbf+DTbf bf16
  ushort16* wqvbf = (ushort16*)(ws + 151191552);        // bf16 Wqv (pre-k2 only) 2,359,296 B
  float*    Cws   = (float*)(ws + 176357376);           // C -> D fp32           12,582,912 B
  float*    klbuf = (float*)(ws + 188940288);           // per-(b,h) KL               1,536 B

  hipLaunchKernelGGL(k0_prep,       dim3(1024), dim3(256), 0, stream, x, Wqv, omega_h, log_ls, xbf, wqvbf, omTbf, klbuf);
  hipLaunchKernelGGL(k1_qv_mfma,    dim3(3072), dim3(256), 0, stream, xbf, wqvbf, qv);
  hipLaunchKernelGGL(k2_gram_mfma,  dim3(BH_),  dim3(256), 0, stream, qv, omTbf, phase, log_sf, Gbase, Cws);
  hipLaunchKernelGGL(k3_factor,     dim3(BH_),  dim3(256), 0, stream, Gbase, Cws, log_s2, klbuf);
  hipLaunchKernelGGL(k4_sample_mfma,dim3(3072), dim3(256), 0, stream, qv, omTbf, phase, log_sf, log_s2, Gbase, eps, sfeat);
  hipLaunchKernelGGL(k5_out_mfma,   dim3(1536), dim3(256), 0, stream, sfeat, Wo, Wob, outp);
  hipLaunchKernelGGL(k6_kl,         dim3(1),    dim3(128), 0, stream, klbuf, outp);
}

// Round 6
// 893.418 us; speedup vs baseline: 1.6103x; 1.6103x over previous
//
#include <hip/hip_runtime.h>
#include <hip/hip_bf16.h>
#include <math.h>

// Problem constants
#define B_   32
#define L_   1024
#define H_   12
#define DV   64
#define MH   64
#define MM   128      // M = 2*Mh
#define HD   768      // hdim
#define BH_  384      // B*H

typedef unsigned int  uint32;
typedef unsigned short ushort16;
typedef __attribute__((ext_vector_type(4))) float f32x4;
typedef __attribute__((ext_vector_type(8))) short bf16x8;

__device__ __forceinline__ float bf2f(uint32 u) {
  return __uint_as_float(u << 16);
}
__device__ __forceinline__ ushort16 f2bf(float f) {
  uint32 x = __float_as_uint(f);
  x += 0x7FFFu + ((x >> 16) & 1u);   // RNE
  return (ushort16)(x >> 16);
}
__device__ __forceinline__ uint32 pack2bf(float a, float b) {
  return (uint32)f2bf(a) | ((uint32)f2bf(b) << 16);
}

// ---------------------------------------------------------------------------
// K0: convert x, Wqv to bf16; omega_scaled bf16 [h][m][d]; zero kl.
// ---------------------------------------------------------------------------
__global__ __launch_bounds__(256)
void k0_prep(const float* __restrict__ x, const float* __restrict__ Wqv,
             const float* __restrict__ omega_half, const float* __restrict__ log_ls,
             ushort16* __restrict__ xbf, ushort16* __restrict__ wqvbf,
             ushort16* __restrict__ omTbf, float* __restrict__ klbuf) {
  size_t i0 = (size_t)blockIdx.x * 256 + threadIdx.x;
  size_t stride = (size_t)gridDim.x * 256;
  for (size_t i = i0; i < (size_t)25165824 / 4; i += stride) {
    float4 v = ((const float4*)x)[i];
    uint2 w; w.x = pack2bf(v.x, v.y); w.y = pack2bf(v.z, v.w);
    ((uint2*)xbf)[i] = w;
  }
  for (size_t i = i0; i < (size_t)1179648 / 4; i += stride) {
    float4 v = ((const float4*)Wqv)[i];
    uint2 w; w.x = pack2bf(v.x, v.y); w.y = pack2bf(v.z, v.w);
    ((uint2*)wqvbf)[i] = w;
  }
  if (blockIdx.x < H_) {
    int h = blockIdx.x;
    for (int e = threadIdx.x; e < MH * DV; e += blockDim.x) {
      int m = e >> 6, d = e & 63;
      float scale = 1.41421356237f * expf(-log_ls[h * DV + d]);
      omTbf[h * MH * DV + m * DV + d] = f2bf(omega_half[h * DV * MH + d * MH + m] * scale);
    }
  }
  if (blockIdx.x == 0) {
    for (int e = threadIdx.x; e < BH_; e += blockDim.x) klbuf[e] = 0.f;
  }
}

// ---------------------------------------------------------------------------
// K1: qv = x @ Wqv^T in bf16 MFMA (16x16x32), 128x128 tile, BK=32.
//     Output bf16 permuted to [b][h][l][c], c in [0,128): c<64=q, c>=64=v.
// ---------------------------------------------------------------------------
__global__ __launch_bounds__(256)
void k1_qv_mfma(const ushort16* __restrict__ xbf, const ushort16* __restrict__ wqvbf,
                ushort16* __restrict__ qv) {
  __shared__ ushort16 As[128 * 40];
  __shared__ ushort16 Bs[128 * 40];
  int tid = threadIdx.x;
  int h  = blockIdx.x % 12;
  int tm = blockIdx.x / 12;
  int m0 = tm * 128;
  int n0 = h * 128;
  int wave = tid >> 6, lane = tid & 63;
  int wy = wave >> 1, wx = wave & 1;
  int mlane = lane & 15, q = lane >> 4;
  f32x4 acc[4][4];
#pragma unroll
  for (int i = 0; i < 4; i++)
#pragma unroll
    for (int j = 0; j < 4; j++) acc[i][j] = (f32x4){0.f, 0.f, 0.f, 0.f};

  int c0 = tid, c1 = tid + 256;
  int rowA0 = c0 >> 2, ka0 = (c0 & 3) * 8;
  int rowA1 = c1 >> 2, ka1 = (c1 & 3) * 8;

  for (int k0 = 0; k0 < HD; k0 += 32) {
    __syncthreads();
    uint4 a0 = *(const uint4*)&xbf[(size_t)(m0 + rowA0) * HD + k0 + ka0];
    uint4 a1 = *(const uint4*)&xbf[(size_t)(m0 + rowA1) * HD + k0 + ka1];
    uint4 b0 = *(const uint4*)&wqvbf[(size_t)(n0 + rowA0) * HD + k0 + ka0];
    uint4 b1 = *(const uint4*)&wqvbf[(size_t)(n0 + rowA1) * HD + k0 + ka1];
    *(uint4*)&As[rowA0 * 40 + ka0] = a0;
    *(uint4*)&As[rowA1 * 40 + ka1] = a1;
    *(uint4*)&Bs[rowA0 * 40 + ka0] = b0;
    *(uint4*)&Bs[rowA1 * 40 + ka1] = b1;
    __syncthreads();
    bf16x8 av[4], bv[4];
#pragma unroll
    for (int i = 0; i < 4; i++)
      av[i] = *(const bf16x8*)&As[(wy * 64 + i * 16 + mlane) * 40 + q * 8];
#pragma unroll
    for (int j = 0; j < 4; j++)
      bv[j] = *(const bf16x8*)&Bs[(wx * 64 + j * 16 + mlane) * 40 + q * 8];
#pragma unroll
    for (int i = 0; i < 4; i++)
#pragma unroll
      for (int j = 0; j < 4; j++)
        acc[i][j] = __builtin_amdgcn_mfma_f32_16x16x32_bf16(av[i], bv[j], acc[i][j], 0, 0, 0);
  }
#pragma unroll
  for (int i = 0; i < 4; i++) {
#pragma unroll
    for (int e = 0; e < 4; e++) {
      int gm = m0 + wy * 64 + i * 16 + q * 4 + e;
      int b = gm >> 10, l = gm & 1023;
      ushort16* dst = qv + ((((size_t)(b * 12 + h) << 10) | (unsigned)l) << 7);
#pragma unroll
      for (int j = 0; j < 4; j++) {
        int c = wx * 64 + j * 16 + mlane;
        dst[c] = f2bf(acc[i][j][e]);
      }
    }
  }
}

// ---------------------------------------------------------------------------
// K2: per (b,h): G = phi^T phi (128x128), C = phi^T v (128x64), all MFMA.
// ---------------------------------------------------------------------------
__global__ __launch_bounds__(256)
void k2_gram_mfma(const ushort16* __restrict__ qv, const ushort16* __restrict__ omTbf,
                  const float* __restrict__ phase, const float* __restrict__ log_sf,
                  char* __restrict__ Gbase, float* __restrict__ Cws) {
  __shared__ ushort16 PhT[128 * 136];   // 34816 B  phi^T [m][l]
  __shared__ ushort16 vT[64 * 136];     // 17408 B  v^T   [d][l]
  __shared__ float phaseS[MH];
  int bh = blockIdx.x;
  int h = bh % H_;
  int tid = threadIdx.x;
  int wave = tid >> 6, lane = tid & 63;
  int ml = lane & 15, qq = lane >> 4;
  if (tid < MH) phaseS[tid] = phase[h * MH + tid];
  float amp = sqrtf(expf(log_sf[h])) * 0.08838834764831845f;  // 1/sqrt(128)
  const ushort16* qp = qv + (size_t)bh * L_ * MM;
  const ushort16* Om = omTbf + h * MH * DV;
  f32x4 gacc[2][8];
  f32x4 cacc[2][4];
#pragma unroll
  for (int i = 0; i < 2; i++) {
#pragma unroll
    for (int j = 0; j < 8; j++) gacc[i][j] = (f32x4){0.f, 0.f, 0.f, 0.f};
#pragma unroll
    for (int j = 0; j < 4; j++) cacc[i][j] = (f32x4){0.f, 0.f, 0.f, 0.f};
  }
  __syncthreads();   // phaseS ready

  for (int l0 = 0; l0 < L_; l0 += 128) {
    // MFMA1: proj for this wave's 32 rows (K=64)
    f32x4 pacc[2][4];
#pragma unroll
    for (int i = 0; i < 2; i++)
#pragma unroll
      for (int j = 0; j < 4; j++) pacc[i][j] = (f32x4){0.f, 0.f, 0.f, 0.f};
#pragma unroll
    for (int k = 0; k < 2; k++) {
      bf16x8 af[2], bfm[4];
#pragma unroll
      for (int i = 0; i < 2; i++)
        af[i] = *(const bf16x8*)&qp[(size_t)(l0 + wave * 32 + i * 16 + ml) * MM + k * 32 + qq * 8];
#pragma unroll
      for (int j = 0; j < 4; j++)
        bfm[j] = *(const bf16x8*)&Om[(j * 16 + ml) * DV + k * 32 + qq * 8];
#pragma unroll
      for (int i = 0; i < 2; i++)
#pragma unroll
        for (int j = 0; j < 4; j++)
          pacc[i][j] = __builtin_amdgcn_mfma_f32_16x16x32_bf16(af[i], bfm[j], pacc[i][j], 0, 0, 0);
    }
    // stage v^T
    for (int u = tid; u < 1024; u += 256) {
      int row = u >> 3, g = u & 7;
      uint4 w = *(const uint4*)&qp[(size_t)(l0 + row) * MM + 64 + g * 8];
      vT[(g * 8 + 0) * 136 + row] = (ushort16)(w.x & 0xffffu);
      vT[(g * 8 + 1) * 136 + row] = (ushort16)(w.x >> 16);
      vT[(g * 8 + 2) * 136 + row] = (ushort16)(w.y & 0xffffu);
      vT[(g * 8 + 3) * 136 + row] = (ushort16)(w.y >> 16);
      vT[(g * 8 + 4) * 136 + row] = (ushort16)(w.z & 0xffffu);
      vT[(g * 8 + 5) * 136 + row] = (ushort16)(w.z >> 16);
      vT[(g * 8 + 6) * 136 + row] = (ushort16)(w.w & 0xffffu);
      vT[(g * 8 + 7) * 136 + row] = (ushort16)(w.w >> 16);
    }
    // phi (transposed store)
#pragma unroll
    for (int i = 0; i < 2; i++)
#pragma unroll
      for (int j = 0; j < 4; j++)
#pragma unroll
        for (int e = 0; e < 4; e++) {
          int l = wave * 32 + i * 16 + qq * 4 + e;   // local row
          int m = j * 16 + ml;
          float s = pacc[i][j][e] + phaseS[m];
          float sv, cv;
          sincosf(s, &sv, &cv);
          PhT[m * 136 + l]        = f2bf(amp * cv);
          PhT[(MH + m) * 136 + l] = f2bf(amp * sv);
        }
    __syncthreads();
    // G += PhT . PhT^T ; C += PhT . vT^T   (K = 128 local l)
#pragma unroll
    for (int k = 0; k < 4; k++) {
      bf16x8 af[2];
#pragma unroll
      for (int i = 0; i < 2; i++)
        af[i] = *(const bf16x8*)&PhT[(wave * 32 + i * 16 + ml) * 136 + k * 32 + qq * 8];
#pragma unroll
      for (int j = 0; j < 8; j++) {
        bf16x8 bfr = *(const bf16x8*)&PhT[(j * 16 + ml) * 136 + k * 32 + qq * 8];
#pragma unroll
        for (int i = 0; i < 2; i++)
          gacc[i][j] = __builtin_amdgcn_mfma_f32_16x16x32_bf16(af[i], bfr, gacc[i][j], 0, 0, 0);
      }
#pragma unroll
      for (int j = 0; j < 4; j++) {
        bf16x8 bvr = *(const bf16x8*)&vT[(j * 16 + ml) * 136 + k * 32 + qq * 8];
#pragma unroll
        for (int i = 0; i < 2; i++)
          cacc[i][j] = __builtin_amdgcn_mfma_f32_16x16x32_bf16(af[i], bvr, cacc[i][j], 0, 0, 0);
      }
    }
    __syncthreads();
  }
  float* Gp = (float*)(Gbase + (size_t)bh * 65536);
#pragma unroll
  for (int i = 0; i < 2; i++)
#pragma unroll
    for (int e = 0; e < 4; e++) {
      int m = wave * 32 + i * 16 + qq * 4 + e;
#pragma unroll
      for (int j = 0; j < 8; j++) Gp[m * MM + j * 16 + ml] = gacc[i][j][e];
    }
  float* Cp = Cws + (size_t)bh * MM * DV;
#pragma unroll
  for (int i = 0; i < 2; i++)
#pragma unroll
    for (int e = 0; e < 4; e++) {
      int m = wave * 32 + i * 16 + qq * 4 + e;
#pragma unroll
      for (int j = 0; j < 4; j++) Cp[m * DV + j * 16 + ml] = cacc[i][j][e];
    }
}

// ---------------------------------------------------------------------------
// K3: per (b,h): blocked Cholesky (NB=16); blocked inversion X = L^-1;
//     writes Xbf (bf16 lower-tri [n][m]) into the G slot; KL logdet +
//     tr(Ainv) + const parts. D/W work moved to k3b (MFMA) — k3 is lean:
//     lower VGPR, smaller code, better latency hiding.
// ---------------------------------------------------------------------------
#define LB_(i,k) LBs[((i) << 7) + (((k) + (i)) & 127)]

__global__ __launch_bounds__(256)
void k3_factor(char* __restrict__ Gbase,
               const float* __restrict__ log_sigma2, float* __restrict__ klbuf) {
  __shared__ float LBs[MM * MM];     // 64 KB exactly
  int bh = blockIdx.x;
  int tid = threadIdx.x;
  float ls = log_sigma2[0];
  float sigma2 = expf(ls);
  float cjit = sigma2 + 1e-6f;
  const float* Gp = (const float*)(Gbase + (size_t)bh * 65536);
  for (int e = tid; e < MM * MM; e += 256) {
    int m = e >> 7, n = e & 127;
    float g = Gp[e];
    if (m == n) g += cjit;
    LB_(m, n) = g;
  }
  float klp = 0.f;

  // ---- Phase 1: blocked right-looking Cholesky, NB=16
  for (int P = 0; P < 8; P++) {
    int p0 = P * 16;
    __syncthreads();
    if (tid < 16) {
      int t = tid;
      float r[16];
#pragma unroll
      for (int k = 0; k < 16; k++) r[k] = LB_(p0 + t, p0 + k);
#pragma unroll
      for (int j = 0; j < 16; j++) {
        float djj = __shfl(r[j], j);
        float sd = sqrtf(djj);
        float rinv = 1.f / sd;
        if (t == j) r[j] = sd;
        else if (t > j) r[j] *= rinv;
#pragma unroll
        for (int k2 = 0; k2 < 16; k2++) {
          if (k2 > j) {
            float lkj = __shfl(r[j], k2);
            if (t >= k2) r[k2] = fmaf(-r[j], lkj, r[k2]);
          }
        }
      }
#pragma unroll
      for (int k = 0; k < 16; k++) if (k <= t) LB_(p0 + t, p0 + k) = r[k];
      klp += 64.f * logf(r[t]);       // 32*logdetA share
    }
    __syncthreads();
    int NR = 112 - p0;
    if (NR > 0 && tid < NR) {
      int gi = p0 + 16 + tid;
      float a[16];
#pragma unroll
      for (int k = 0; k < 16; k++) a[k] = LB_(gi, p0 + k);
#pragma unroll
      for (int j = 0; j < 16; j++) {
        float inv = 1.f / LB_(p0 + j, p0 + j);
        a[j] *= inv;
#pragma unroll
        for (int k = 0; k < 16; k++)
          if (k > j) a[k] = fmaf(-a[j], LB_(p0 + k, p0 + j), a[k]);
      }
#pragma unroll
      for (int k = 0; k < 16; k++) LB_(gi, p0 + k) = a[k];
    }
    __syncthreads();
    int S = NR;
    if (S > 0) {
      int base = p0 + 16;
      int t4 = S >> 2;
      int ntiles = t4 * t4;
      for (int tt = tid; tt < ntiles; tt += 256) {
        int ti = tt / t4, tj = tt % t4;
        if (ti < tj) continue;
        int gi = base + ti * 4, gj = base + tj * 4;
        float acc[4][4] = {};
#pragma unroll
        for (int j = 0; j < 16; j++) {
          float pa[4], pb[4];
#pragma unroll
          for (int a2 = 0; a2 < 4; a2++) pa[a2] = LB_(gi + a2, p0 + j);
#pragma unroll
          for (int b2 = 0; b2 < 4; b2++) pb[b2] = LB_(gj + b2, p0 + j);
#pragma unroll
          for (int a2 = 0; a2 < 4; a2++)
#pragma unroll
            for (int b2 = 0; b2 < 4; b2++)
              acc[a2][b2] = fmaf(pa[a2], pb[b2], acc[a2][b2]);
        }
#pragma unroll
        for (int a2 = 0; a2 < 4; a2++)
#pragma unroll
          for (int b2 = 0; b2 < 4; b2++)
            LB_(gi + a2, gj + b2) -= acc[a2][b2];
      }
    }
  }
  __syncthreads();

  // ---- Phase 2: invert the 8 diag blocks in place (zero-filled upper)
  {
    float xk[16];
    int cb = tid >> 4, cc = tid & 15;
    if (tid < 128) {
      int g = cb * 16;
#pragma unroll
      for (int rr = 0; rr < 16; rr++) {
        float s = (rr == cc) ? 1.f : 0.f;
#pragma unroll
        for (int k = 0; k < 16; k++)
          if (k < rr) s = fmaf(-LB_(g + rr, g + k), xk[k], s);
        xk[rr] = (rr >= cc) ? s / LB_(g + rr, g + rr) : 0.f;
      }
    }
    __syncthreads();
    if (tid < 128) {
      int g = cb * 16;
#pragma unroll
      for (int rr = 0; rr < 16; rr++) LB_(g + rr, g + cc) = xk[rr];
    }
    __syncthreads();
  }

  // ---- Phase 3: off-diag blocks of X = L^-1
  {
    int r16 = tid >> 4, c16 = tid & 15;
    for (int J = 6; J >= 0; J--) {
      int nb = 7 - J;
      float yv[7];
#pragma unroll
      for (int q = 0; q < 7; q++) {
        if (q < nb) {
          int K = J + 1 + q;
          float s = 0.f;
#pragma unroll
          for (int c2 = 0; c2 < 16; c2++)
            s = fmaf(LB_(K * 16 + r16, J * 16 + c2), LB_(J * 16 + c2, J * 16 + c16), s);
          yv[q] = s;
        }
      }
      __syncthreads();
#pragma unroll
      for (int q = 0; q < 7; q++)
        if (q < nb) LB_((J + 1 + q) * 16 + r16, J * 16 + c16) = yv[q];
      __syncthreads();
      float xv[7];
#pragma unroll
      for (int q = 0; q < 7; q++) {
        if (q < nb) {
          int I = J + 1 + q;
          float s = 0.f;
          for (int K = J + 1; K <= I; K++) {
#pragma unroll
            for (int k = 0; k < 16; k++)
              s = fmaf(LB_(I * 16 + r16, K * 16 + k), LB_(K * 16 + k, J * 16 + c16), s);
          }
          xv[q] = -s;
        }
      }
      __syncthreads();
#pragma unroll
      for (int q = 0; q < 7; q++)
        if (q < nb) LB_((J + 1 + q) * 16 + r16, J * 16 + c16) = xv[q];
      __syncthreads();
    }
  }

  // ---- Phase 4: write Xbf (bf16, zeros above diag); tr(Ainv) = ||X||_F^2
  ushort16* Xb = (ushort16*)(Gbase + (size_t)bh * 65536);
  for (int e = tid; e < MM * MM; e += 256) {
    int r = e >> 7, c = e & 127;
    float xv2 = (c <= r) ? LB_(r, c) : 0.f;
    Xb[e] = f2bf(xv2);
    klp += 32.f * sigma2 * xv2 * xv2;
  }
  if (tid == 0) klp += -4096.f - 4096.f * ls;   // 0.5*(-k - Dv*M*log(sigma2))
  atomicAdd(&klbuf[bh], klp);
}

// ---------------------------------------------------------------------------
// K3b: per (b,h), all-MFMA: D = X·C (X bf16 rows from Gbase global — the
//      proven k3->k4 edge; C^T staged bf16 in LDS), D^T parked in LDS
//      (reusing C^T's space), DTbf written coalesced, W^T = D^T·X via MFMA
//      (X^T staged in LDS), mu_norm2 = ||W||^2 -> klbuf. 52 KB LDS.
// ---------------------------------------------------------------------------
__global__ __launch_bounds__(256)
void k3b_dw(const char* __restrict__ Gbase, const float* __restrict__ Cws,
            float* __restrict__ klbuf) {
  __shared__ ushort16 XTl[128 * 136];   // 34816 B  X^T bf16 [m][n]
  __shared__ ushort16 CTD[64 * 136];    // 17408 B  C^T [d][m], then D^T [d][n]
  int bh = blockIdx.x;
  int tid = threadIdx.x;
  int wave = tid >> 6, lane = tid & 63;
  int ml = lane & 15, qq = lane >> 4;
  const ushort16* Xb = (const ushort16*)(Gbase + (size_t)bh * 65536);
  ushort16* DTb = (ushort16*)(Gbase + (size_t)bh * 65536 + 32768);
  const float* Cp = Cws + (size_t)bh * MM * DV;

  // stage C^T[d][m] = bf16(C[m][d])
  for (int e = tid; e < 1024; e += 256) {
    int m = e >> 3, g = e & 7;
    float4 w0 = *(const float4*)&Cp[m * 64 + g * 8];
    float4 w1 = *(const float4*)&Cp[m * 64 + g * 8 + 4];
    CTD[(g * 8 + 0) * 136 + m] = f2bf(w0.x);
    CTD[(g * 8 + 1) * 136 + m] = f2bf(w0.y);
    CTD[(g * 8 + 2) * 136 + m] = f2bf(w0.z);
    CTD[(g * 8 + 3) * 136 + m] = f2bf(w0.w);
    CTD[(g * 8 + 4) * 136 + m] = f2bf(w1.x);
    CTD[(g * 8 + 5) * 136 + m] = f2bf(w1.y);
    CTD[(g * 8 + 6) * 136 + m] = f2bf(w1.z);
    CTD[(g * 8 + 7) * 136 + m] = f2bf(w1.w);
  }
  // stage X^T[m][n] = Xb[n][m]  (k2 vT unpack pattern)
  for (int e = tid; e < 2048; e += 256) {
    int n = e >> 4, g = e & 15;
    uint4 w = *(const uint4*)&Xb[n * MM + g * 8];
    XTl[(g * 8 + 0) * 136 + n] = (ushort16)(w.x & 0xffffu);
    XTl[(g * 8 + 1) * 136 + n] = (ushort16)(w.x >> 16);
    XTl[(g * 8 + 2) * 136 + n] = (ushort16)(w.y & 0xffffu);
    XTl[(g * 8 + 3) * 136 + n] = (ushort16)(w.y >> 16);
    XTl[(g * 8 + 4) * 136 + n] = (ushort16)(w.z & 0xffffu);
    XTl[(g * 8 + 5) * 136 + n] = (ushort16)(w.z >> 16);
    XTl[(g * 8 + 6) * 136 + n] = (ushort16)(w.w & 0xffffu);
    XTl[(g * 8 + 7) * 136 + n] = (ushort16)(w.w >> 16);
  }
  __syncthreads();

  // MFMA-1: D[n][d] = sum_m X[n][m] * C^T[d][m].  Wave owns rows
  // n in [wave*32, wave*32+32): acc[2][4]; A rows from global Xb (L2-hot).
  f32x4 dacc[2][4];
#pragma unroll
  for (int i = 0; i < 2; i++)
#pragma unroll
    for (int j = 0; j < 4; j++) dacc[i][j] = (f32x4){0.f, 0.f, 0.f, 0.f};
#pragma unroll
  for (int k = 0; k < 4; k++) {
    bf16x8 af[2];
#pragma unroll
    for (int i = 0; i < 2; i++)
      af[i] = *(const bf16x8*)&Xb[(wave * 32 + i * 16 + ml) * MM + k * 32 + qq * 8];
#pragma unroll
    for (int j = 0; j < 4; j++) {
      bf16x8 bfr = *(const bf16x8*)&CTD[(j * 16 + ml) * 136 + k * 32 + qq * 8];
#pragma unroll
      for (int i = 0; i < 2; i++)
        dacc[i][j] = __builtin_amdgcn_mfma_f32_16x16x32_bf16(af[i], bfr, dacc[i][j], 0, 0, 0);
    }
  }
  __syncthreads();   // all C^T reads done; CTD space now free for D^T

  // D^T[d][n] store (transposed, per-element — k2 PhT pattern)
#pragma unroll
  for (int i = 0; i < 2; i++)
#pragma unroll
    for (int j = 0; j < 4; j++)
#pragma unroll
      for (int e = 0; e < 4; e++) {
        int n = wave * 32 + i * 16 + qq * 4 + e;
        int d = j * 16 + ml;
        CTD[d * 136 + n] = f2bf(dacc[i][j][e]);
      }
  __syncthreads();   // D^T complete

  // MFMA-2: W^T[d][m] = sum_n D^T[d][n] * X^T[m][n].  Wave owns d rows
  // [wave*16, wave*16+16): wacc[8] covers all 128 m-cols.
  f32x4 wacc[8];
#pragma unroll
  for (int j = 0; j < 8; j++) wacc[j] = (f32x4){0.f, 0.f, 0.f, 0.f};
#pragma unroll
  for (int k = 0; k < 4; k++) {
    bf16x8 afD = *(const bf16x8*)&CTD[(wave * 16 + ml) * 136 + k * 32 + qq * 8];
#pragma unroll
    for (int j = 0; j < 8; j++) {
      bf16x8 bfX = *(const bf16x8*)&XTl[(j * 16 + ml) * 136 + k * 32 + qq * 8];
      wacc[j] = __builtin_amdgcn_mfma_f32_16x16x32_bf16(afD, bfX, wacc[j], 0, 0, 0);
    }
  }
  // mu_norm2 partial: every wacc element is a distinct W entry
  float klp = 0.f;
#pragma unroll
  for (int j = 0; j < 8; j++)
#pragma unroll
    for (int e = 0; e < 4; e++) klp += 0.5f * wacc[j][e] * wacc[j][e];
  klp += __shfl_xor(klp, 1);
  klp += __shfl_xor(klp, 2);
  klp += __shfl_xor(klp, 4);
  klp += __shfl_xor(klp, 8);
  klp += __shfl_xor(klp, 16);
  klp += __shfl_xor(klp, 32);
  if (lane == 0) atomicAdd(&klbuf[bh], klp);

  // DTbf coalesced write from LDS
  for (int u = tid; u < 1024; u += 256) {
    int d = u >> 4, g = u & 15;
    *(uint4*)&DTb[d * MM + g * 8] = *(const uint4*)&CTD[d * 136 + g * 8];
  }
}

// ---------------------------------------------------------------------------
// K4: per (bh, 128-row chunk): proj=q@Om^T (MFMA) -> sincos -> phi(LDS) ->
//     z = phi @ X^T (MFMA, X from global bf16) -> var rowsum+shfl ->
//     mean = z @ DT^T (MFMA) -> sample -> coalesced store via LDS.
// ---------------------------------------------------------------------------
__global__ __launch_bounds__(256)
void k4_sample_mfma(const ushort16* __restrict__ qv, const ushort16* __restrict__ omTbf,
                    const float* __restrict__ phase, const float* __restrict__ log_sf,
                    const float* __restrict__ log_sigma2, const char* __restrict__ Gbase,
                    const float* __restrict__ eps, ushort16* __restrict__ sfeat) {
  __shared__ ushort16 ABuf[128 * 136];   // 34816 B  phi, then z (bf16, [l][·])
  __shared__ ushort16 obuf[128 * 72];    // 18432 B  sample staging
  __shared__ float stdS[128];
  __shared__ float phaseS[MH];
  int blk = blockIdx.x;
  int bh = blk >> 3, l0 = (blk & 7) << 7;
  int h = bh % H_, b = bh / H_;
  int tid = threadIdx.x;
  int wave = tid >> 6, lane = tid & 63;
  int ml = lane & 15, qq = lane >> 4;
  if (tid < MH) phaseS[tid] = phase[h * MH + tid];
  float amp = sqrtf(expf(log_sf[h])) * 0.08838834764831845f;
  float sigma2 = expf(log_sigma2[0]);
  const ushort16* qp = qv + ((size_t)bh * L_ + l0) * MM;
  const ushort16* Om = omTbf + h * MH * DV;
  const ushort16* Xb = (const ushort16*)(Gbase + (size_t)bh * 65536);
  const ushort16* DT = (const ushort16*)(Gbase + (size_t)bh * 65536 + 32768);

  // MFMA1: proj (K=64)
  f32x4 pacc[2][4];
#pragma unroll
  for (int i = 0; i < 2; i++)
#pragma unroll
    for (int j = 0; j < 4; j++) pacc[i][j] = (f32x4){0.f, 0.f, 0.f, 0.f};
#pragma unroll
  for (int k = 0; k < 2; k++) {
    bf16x8 af[2], bfm[4];
#pragma unroll
    for (int i = 0; i < 2; i++)
      af[i] = *(const bf16x8*)&qp[(size_t)(wave * 32 + i * 16 + ml) * MM + k * 32 + qq * 8];
#pragma unroll
    for (int j = 0; j < 4; j++)
      bfm[j] = *(const bf16x8*)&Om[(j * 16 + ml) * DV + k * 32 + qq * 8];
#pragma unroll
    for (int i = 0; i < 2; i++)
#pragma unroll
      for (int j = 0; j < 4; j++)
        pacc[i][j] = __builtin_amdgcn_mfma_f32_16x16x32_bf16(af[i], bfm[j], pacc[i][j], 0, 0, 0);
  }
  __syncthreads();   // phaseS ready
  // sincos -> phi rows (wave-private rows of ABuf)
#pragma unroll
  for (int i = 0; i < 2; i++)
#pragma unroll
    for (int j = 0; j < 4; j++)
#pragma unroll
      for (int e = 0; e < 4; e++) {
        int l = wave * 32 + i * 16 + qq * 4 + e;
        int m = j * 16 + ml;
        float s = pacc[i][j][e] + phaseS[m];
        float sv, cv;
        sincosf(s, &sv, &cv);
        ABuf[l * 136 + m]      = f2bf(amp * cv);
        ABuf[l * 136 + 64 + m] = f2bf(amp * sv);
      }
  // MFMA2: z = phi @ X^T (K=128)
  f32x4 zacc[2][8];
#pragma unroll
  for (int i = 0; i < 2; i++)
#pragma unroll
    for (int j = 0; j < 8; j++) zacc[i][j] = (f32x4){0.f, 0.f, 0.f, 0.f};
#pragma unroll
  for (int k = 0; k < 4; k++) {
    bf16x8 af[2];
#pragma unroll
    for (int i = 0; i < 2; i++)
      af[i] = *(const bf16x8*)&ABuf[(wave * 32 + i * 16 + ml) * 136 + k * 32 + qq * 8];
#pragma unroll
    for (int j = 0; j < 8; j++) {
      bf16x8 bfr = *(const bf16x8*)&Xb[(j * 16 + ml) * MM + k * 32 + qq * 8];
#pragma unroll
      for (int i = 0; i < 2; i++)
        zacc[i][j] = __builtin_amdgcn_mfma_f32_16x16x32_bf16(af[i], bfr, zacc[i][j], 0, 0, 0);
    }
  }
  // var = sigma2 * ||z_row||^2 ; std to LDS
#pragma unroll
  for (int i = 0; i < 2; i++)
#pragma unroll
    for (int e = 0; e < 4; e++) {
      float vs = 0.f;
#pragma unroll
      for (int j = 0; j < 8; j++) vs += zacc[i][j][e] * zacc[i][j][e];
      vs += __shfl_xor(vs, 1);
      vs += __shfl_xor(vs, 2);
      vs += __shfl_xor(vs, 4);
      vs += __shfl_xor(vs, 8);
      if (ml == 0) stdS[wave * 32 + i * 16 + qq * 4 + e] = sqrtf(fmaxf(sigma2 * vs, 0.f));
    }
  // z -> ABuf (overwrite phi; wave-private rows)
#pragma unroll
  for (int i = 0; i < 2; i++)
#pragma unroll
    for (int j = 0; j < 8; j++)
#pragma unroll
      for (int e = 0; e < 4; e++) {
        int l = wave * 32 + i * 16 + qq * 4 + e;
        ABuf[l * 136 + j * 16 + ml] = f2bf(zacc[i][j][e]);
      }
  // MFMA3: mean = z @ DT^T (K=128)
  f32x4 macc[2][4];
#pragma unroll
  for (int i = 0; i < 2; i++)
#pragma unroll
    for (int j = 0; j < 4; j++) macc[i][j] = (f32x4){0.f, 0.f, 0.f, 0.f};
#pragma unroll
  for (int k = 0; k < 4; k++) {
    bf16x8 af[2];
#pragma unroll
    for (int i = 0; i < 2; i++)
      af[i] = *(const bf16x8*)&ABuf[(wave * 32 + i * 16 + ml) * 136 + k * 32 + qq * 8];
#pragma unroll
    for (int j = 0; j < 4; j++) {
      bf16x8 bfr = *(const bf16x8*)&DT[(j * 16 + ml) * MM + k * 32 + qq * 8];
#pragma unroll
      for (int i = 0; i < 2; i++)
        macc[i][j] = __builtin_amdgcn_mfma_f32_16x16x32_bf16(af[i], bfr, macc[i][j], 0, 0, 0);
    }
  }
  // sample + stage
  const float* ep = eps + ((size_t)bh * L_ + l0) * DV;
#pragma unroll
  for (int i = 0; i < 2; i++)
#pragma unroll
    for (int j = 0; j < 4; j++)
#pragma unroll
      for (int e = 0; e < 4; e++) {
        int l = wave * 32 + i * 16 + qq * 4 + e;
        int d = j * 16 + ml;
        float smp = macc[i][j][e] + stdS[l] * ep[l * DV + d];
        obuf[l * 72 + d] = f2bf(smp);
      }
  __syncthreads();
  // coalesced store: row = 64 bf16 = 4 uint4
  ushort16* sp = sfeat + ((size_t)b * L_ + l0) * HD + h * DV;
  for (int u = tid; u < 512; u += 256) {
    int row = u >> 2, part = u & 3;
    uint4 val = *(const uint4*)&obuf[row * 72 + part * 8];
    *(uint4*)&sp[(size_t)row * HD + part * 8] = val;
  }
}

// ---------------------------------------------------------------------------
// K5: out = sfeat @ Wo^T + b, bf16 MFMA (Wo converted during staging), fp32 out
// ---------------------------------------------------------------------------
__global__ __launch_bounds__(256)
void k5_out_mfma(const ushort16* __restrict__ sfeat, const float* __restrict__ Wo,
                 const float* __restrict__ bias, float* __restrict__ outp) {
  __shared__ ushort16 As[128 * 40];
  __shared__ ushort16 Bs[128 * 40];
  int tid = threadIdx.x;
  int tn = blockIdx.x % 6;
  int tm = blockIdx.x / 6;
  int m0 = tm * 128, n0 = tn * 128;
  int wave = tid >> 6, lane = tid & 63;
  int wy = wave >> 1, wx = wave & 1;
  int mlane = lane & 15, q = lane >> 4;
  f32x4 acc[4][4];
#pragma unroll
  for (int i = 0; i < 4; i++)
#pragma unroll
    for (int j = 0; j < 4; j++) acc[i][j] = (f32x4){0.f, 0.f, 0.f, 0.f};

  int c0 = tid, c1 = tid + 256;
  int rowA0 = c0 >> 2, ka0 = (c0 & 3) * 8;
  int rowA1 = c1 >> 2, ka1 = (c1 & 3) * 8;

  for (int k0 = 0; k0 < HD; k0 += 32) {
    __syncthreads();
    uint4 a0 = *(const uint4*)&sfeat[(size_t)(m0 + rowA0) * HD + k0 + ka0];
    uint4 a1 = *(const uint4*)&sfeat[(size_t)(m0 + rowA1) * HD + k0 + ka1];
    float4 w00 = *(const float4*)&Wo[(size_t)(n0 + rowA0) * HD + k0 + ka0];
    float4 w01 = *(const float4*)&Wo[(size_t)(n0 + rowA0) * HD + k0 + ka0 + 4];
    float4 w10 = *(const float4*)&Wo[(size_t)(n0 + rowA1) * HD + k0 + ka1];
    float4 w11 = *(const float4*)&Wo[(size_t)(n0 + rowA1) * HD + k0 + ka1 + 4];
    uint4 b0, b1;
    b0.x = pack2bf(w00.x, w00.y); b0.y = pack2bf(w00.z, w00.w);
    b0.z = pack2bf(w01.x, w01.y); b0.w = pack2bf(w01.z, w01.w);
    b1.x = pack2bf(w10.x, w10.y); b1.y = pack2bf(w10.z, w10.w);
    b1.z = pack2bf(w11.x, w11.y); b1.w = pack2bf(w11.z, w11.w);
    *(uint4*)&As[rowA0 * 40 + ka0] = a0;
    *(uint4*)&As[rowA1 * 40 + ka1] = a1;
    *(uint4*)&Bs[rowA0 * 40 + ka0] = b0;
    *(uint4*)&Bs[rowA1 * 40 + ka1] = b1;
    __syncthreads();
    bf16x8 av[4], bv[4];
#pragma unroll
    for (int i = 0; i < 4; i++)
      av[i] = *(const bf16x8*)&As[(wy * 64 + i * 16 + mlane) * 40 + q * 8];
#pragma unroll
    for (int j = 0; j < 4; j++)
      bv[j] = *(const bf16x8*)&Bs[(wx * 64 + j * 16 + mlane) * 40 + q * 8];
#pragma unroll
    for (int i = 0; i < 4; i++)
#pragma unroll
      for (int j = 0; j < 4; j++)
        acc[i][j] = __builtin_amdgcn_mfma_f32_16x16x32_bf16(av[i], bv[j], acc[i][j], 0, 0, 0);
  }
  float bsv[4];
#pragma unroll
  for (int j = 0; j < 4; j++) bsv[j] = bias[n0 + wx * 64 + j * 16 + mlane];
#pragma unroll
  for (int i = 0; i < 4; i++) {
#pragma unroll
    for (int e = 0; e < 4; e++) {
      int gm = m0 + wy * 64 + i * 16 + q * 4 + e;
#pragma unroll
      for (int j = 0; j < 4; j++) {
        int gn = n0 + wx * 64 + j * 16 + mlane;
        outp[(size_t)gm * HD + gn] = acc[i][j][e] + bsv[j];
      }
    }
  }
}

// ---------------------------------------------------------------------------
// K6: kl = sum(klbuf)/B  -> out[25165824]
// ---------------------------------------------------------------------------
__global__ void k6_kl(const float* __restrict__ klbuf, float* __restrict__ outp) {
  __shared__ float red[2];
  int tid = threadIdx.x;   // 128
  float s = 0.f;
  for (int e = tid; e < BH_; e += 128) s += klbuf[e];
  for (int off = 32; off >= 1; off >>= 1) s += __shfl_xor(s, off);
  if ((tid & 63) == 0) red[tid >> 6] = s;
  __syncthreads();
  if (tid == 0) outp[(size_t)B_ * L_ * HD] = (red[0] + red[1]) * (1.f / 32.f);
}

// ---------------------------------------------------------------------------
extern "C" void kernel_launch(void* const* d_in, const int* in_sizes, int n_in,
                              void* d_out, int out_size, void* d_ws, size_t ws_size,
                              hipStream_t stream) {
  (void)in_sizes; (void)n_in; (void)out_size; (void)ws_size;
  const float* x       = (const float*)d_in[0];
  const float* Wqv     = (const float*)d_in[1];
  const float* log_sf  = (const float*)d_in[2];
  const float* log_ls  = (const float*)d_in[3];
  const float* log_s2  = (const float*)d_in[4];
  const float* omega_h = (const float*)d_in[5];
  const float* phase   = (const float*)d_in[6];
  const float* Wo      = (const float*)d_in[7];
  const float* Wob     = (const float*)d_in[8];
  const float* eps     = (const float*)d_in[9];
  float* outp = (float*)d_out;

  // Workspace layout (total 188,941,824 bytes):
  char* ws = (char*)d_ws;
  ushort16* qv    = (ushort16*)(ws);                    // bf16 [b][h][l][128]  100,663,296 B
  ushort16* xbf   = (ushort16*)(ws + 100663296);        // bf16 x; later sfeat   50,331,648 B
  ushort16* sfeat = xbf;                                // alias (k1 done with xbf before k4)
  ushort16* omTbf = (ushort16*)(ws + 150994944);        // bf16 [h][m][d]            98,304 B
  char*     Gbase = ws + 151191552;                     // 384 x 65536 B slots:
                                                        //  G fp32 -> Xbf+DTbf bf16
  ushort16* wqvbf = (ushort16*)(ws + 151191552);        // bf16 Wqv (pre-k2 only) 2,359,296 B
  float*    Cws   = (float*)(ws + 176357376);           // C fp32 (read-only after k2) 12,582,912 B
  float*    klbuf = (float*)(ws + 188940288);           // per-(b,h) KL               1,536 B

  hipLaunchKernelGGL(k0_prep,       dim3(1024), dim3(256), 0, stream, x, Wqv, omega_h, log_ls, xbf, wqvbf, omTbf, klbuf);
  hipLaunchKernelGGL(k1_qv_mfma,    dim3(3072), dim3(256), 0, stream, xbf, wqvbf, qv);
  hipLaunchKernelGGL(k2_gram_mfma,  dim3(BH_),  dim3(256), 0, stream, qv, omTbf, phase, log_sf, Gbase, Cws);
  hipLaunchKernelGGL(k3_factor,     dim3(BH_),  dim3(256), 0, stream, Gbase, log_s2, klbuf);
  hipLaunchKernelGGL(k3b_dw,        dim3(BH_),  dim3(256), 0, stream, Gbase, Cws, klbuf);
  hipLaunchKernelGGL(k4_sample_mfma,dim3(3072), dim3(256), 0, stream, qv, omTbf, phase, log_sf, log_s2, Gbase, eps, sfeat);
  hipLaunchKernelGGL(k5_out_mfma,   dim3(1536), dim3(256), 0, stream, sfeat, Wo, Wob, outp);
  hipLaunchKernelGGL(k6_kl,         dim3(1),    dim3(128), 0, stream, klbuf, outp);
}